// Round 2
// baseline (2685.480 us; speedup 1.0000x reference)
//
#include <hip/hip_runtime.h>
#include <math.h>

#define E_TOT 200000
#define NNODE 12500
#define DD 128
#define G3 384
#define NRB 20
#define TM 64            // edges per block tile
#define NTHR 256

// ---- device scratch for counting sort (avoids workspace-size assumptions) ----
__device__ int d_cnt[NNODE];
__device__ int d_offs[NNODE];
__device__ int d_perm[E_TOT];

// ---------------- kernel 0: zero the histogram --------------------------------
__global__ void zero_kernel() {
    int i = blockIdx.x * blockDim.x + threadIdx.x;
    if (i < NNODE) d_cnt[i] = 0;
}

// ---------------- kernel 1: global sum-of-squares of r + node histogram -------
__global__ void prep_kernel(const float* __restrict__ r,
                            const int* __restrict__ idx_i,
                            float* __restrict__ ws) {
    const int tid = blockIdx.x * blockDim.x + threadIdx.x;
    const int stride = gridDim.x * blockDim.x;
    const int n = E_TOT * 3;
    float acc = 0.f;
    for (int i = tid; i < n; i += stride) {
        float x = r[i];
        acc += x * x;
    }
    #pragma unroll
    for (int off = 32; off > 0; off >>= 1)
        acc += __shfl_down(acc, off, 64);
    __shared__ float wsum[4];
    int lane = threadIdx.x & 63, wid = threadIdx.x >> 6;
    if (lane == 0) wsum[wid] = acc;
    __syncthreads();
    if (threadIdx.x == 0)
        atomicAdd(ws, wsum[0] + wsum[1] + wsum[2] + wsum[3]);
    // histogram of destination nodes
    for (int e = tid; e < E_TOT; e += stride)
        atomicAdd(&d_cnt[idx_i[e]], 1);
}

// ---------------- kernel 2: exclusive prefix sum over 12500 bins --------------
__global__ void scan_kernel() {
    __shared__ int part[NTHR];
    const int per = (NNODE + NTHR - 1) / NTHR;   // 49
    const int t = threadIdx.x;
    const int lo = t * per;
    const int hi = (lo + per < NNODE) ? lo + per : NNODE;
    int sum = 0;
    for (int i = lo; i < hi; ++i) sum += d_cnt[i];
    part[t] = sum;
    __syncthreads();
    if (t == 0) {
        int acc = 0;
        for (int k = 0; k < NTHR; ++k) { int c = part[k]; part[k] = acc; acc += c; }
    }
    __syncthreads();
    int acc = part[t];
    for (int i = lo; i < hi; ++i) { int c = d_cnt[i]; d_offs[i] = acc; acc += c; }
}

// ---------------- kernel 3: scatter edge ids into node-sorted order -----------
__global__ void scatter_kernel(const int* __restrict__ idx_i) {
    const int tid = blockIdx.x * blockDim.x + threadIdx.x;
    const int stride = gridDim.x * blockDim.x;
    for (int e = tid; e < E_TOT; e += stride) {
        int p = atomicAdd(&d_offs[idx_i[e]], 1);
        d_perm[p] = e;
    }
}

// ---------------- kernel 4: fused per-edge MLP + gating + aggregated scatter --
// per block: TM=64 edges (in node-sorted order via d_perm).
// LDS: sS[64][132] (S tile, then H tile, then fcut/org/idx),
// sB[384*20] union buffer (W1 chunks / W2 chunks / Ww), sPerm[64].
__global__ __launch_bounds__(NTHR, 2) void fused_kernel(
    const float* __restrict__ s, const float* __restrict__ r,
    const float* __restrict__ v, const float* __restrict__ W1,
    const float* __restrict__ b1, const float* __restrict__ W2,
    const float* __restrict__ b2, const float* __restrict__ Ww,
    const float* __restrict__ bw, const int* __restrict__ idx_i,
    const float* __restrict__ ws, float* __restrict__ out)
{
    __shared__ float sS[TM][DD + 4];     // 64 x 132 = 33792 B
    __shared__ float sB[G3 * 20];        // 30720 B
    __shared__ int   sPerm[TM];          // 256 B
    // aliases into sS storage, used only AFTER phase 2 (H is dead then)
    float* sFc  = &sS[0][0];                    // [64][20]
    float* sOrg = &sS[0][0] + TM * NRB;         // [64][3]
    int*   sIdx = (int*)(&sS[0][0] + TM * NRB + TM * 3);

    const int t   = threadIdx.x;
    const int e0g = blockIdx.x * TM;

    // ---- stage permutation for this tile ----
    if (t < TM) sPerm[t] = d_perm[e0g + t];
    __syncthreads();

    // ---- stage S tile (64 x 128 f32), coalesced float4 per row ----
    #pragma unroll
    for (int u = 0; u < 8; ++u) {
        int fi   = t + NTHR * u;         // float4 index 0..2047
        int row  = fi >> 5;              // 32 float4 per row
        int col4 = fi & 31;
        float4 val = reinterpret_cast<const float4*>(s)[(size_t)sPerm[row] * 32 + col4];
        *reinterpret_cast<float4*>(&sS[row][col4 * 4]) = val;
    }

    // ================= phase 1: H = silu(S @ W1^T + b1) =================
    const int tf  = t & 15;              // f lane base; f = tf + 16*j
    const int te1 = t >> 4;              // 0..15
    const int e1  = te1 * 4;             // 4 edges per thread
    float acc1[4][8];
    #pragma unroll
    for (int j = 0; j < 8; ++j) {
        float bias = b1[tf + 16 * j];
        #pragma unroll
        for (int i = 0; i < 4; ++i) acc1[i][j] = bias;
    }
    for (int kk = 0; kk < DD; kk += 16) {
        __syncthreads();                 // prev chunk reads done (also covers S staging)
        {   // load W1 chunk rows f=0..127, k'=0..15 into sB[f*20 + k']
            int f = t >> 1;
            int kb = (t & 1) * 8;
            const float4* src = reinterpret_cast<const float4*>(&W1[f * DD + kk + kb]);
            float4 v0 = src[0], v1 = src[1];
            *reinterpret_cast<float4*>(&sB[f * 20 + kb])     = v0;
            *reinterpret_cast<float4*>(&sB[f * 20 + kb + 4]) = v1;
        }
        __syncthreads();
        #pragma unroll
        for (int u = 0; u < 4; ++u) {
            float4 a[4], b[8];
            #pragma unroll
            for (int i = 0; i < 4; ++i)
                a[i] = *reinterpret_cast<const float4*>(&sS[e1 + i][kk + 4 * u]);
            #pragma unroll
            for (int j = 0; j < 8; ++j)
                b[j] = *reinterpret_cast<const float4*>(&sB[(tf + 16 * j) * 20 + 4 * u]);
            #pragma unroll
            for (int i = 0; i < 4; ++i)
                #pragma unroll
                for (int j = 0; j < 8; ++j)
                    acc1[i][j] += a[i].x * b[j].x + a[i].y * b[j].y
                                + a[i].z * b[j].z + a[i].w * b[j].w;
        }
    }
    __syncthreads();
    // silu, write H back into sS (S dead)
    #pragma unroll
    for (int i = 0; i < 4; ++i)
        #pragma unroll
        for (int j = 0; j < 8; ++j) {
            float x = acc1[i][j];
            sS[e1 + i][tf + 16 * j] = x / (1.0f + expf(-x));
        }

    // ================= phase 2: PHI = H @ W2^T + b2 (384 outputs) =================
    const int td  = t & 31;              // d lane; d = td + 32*j
    const int te2 = t >> 5;              // 0..7
    const int e2  = te2 * 8;             // 8 edges per thread
    float acc2[8][12];                   // slot q = j*3 + c ; g = td + 32*j + 128*c
    #pragma unroll
    for (int j = 0; j < 4; ++j)
        #pragma unroll
        for (int c = 0; c < 3; ++c) {
            float bias = b2[td + 32 * j + 128 * c];
            #pragma unroll
            for (int i = 0; i < 8; ++i) acc2[i][j * 3 + c] = bias;
        }
    for (int kk = 0; kk < DD; kk += 16) {
        __syncthreads();
        {   // load W2 chunk rows g=0..383, k'=0..15 into sB[g*20 + k']
            #pragma unroll
            for (int u = 0; u < 6; ++u) {
                int fi = t + NTHR * u;   // 0..1535 float4s
                int g  = fi >> 2;
                int k4 = (fi & 3) * 4;
                float4 val = *reinterpret_cast<const float4*>(&W2[g * DD + kk + k4]);
                *reinterpret_cast<float4*>(&sB[g * 20 + k4]) = val;
            }
        }
        __syncthreads();
        #pragma unroll
        for (int u = 0; u < 4; ++u) {
            float4 bfr[12];
            #pragma unroll
            for (int j = 0; j < 4; ++j)
                #pragma unroll
                for (int c = 0; c < 3; ++c)
                    bfr[j * 3 + c] = *reinterpret_cast<const float4*>(
                        &sB[(td + 32 * j + 128 * c) * 20 + 4 * u]);
            #pragma unroll
            for (int i = 0; i < 8; ++i) {
                float4 a = *reinterpret_cast<const float4*>(&sS[e2 + i][kk + 4 * u]);
                #pragma unroll
                for (int q = 0; q < 12; ++q)
                    acc2[i][q] += a.x * bfr[q].x + a.y * bfr[q].y
                                + a.z * bfr[q].z + a.w * bfr[q].w;
            }
        }
    }
    __syncthreads();   // phase-2 LDS reads done; sS and sB now reusable

    // ---- load Ww into sB; compute fcut / org / idx into sS alias ----
    #pragma unroll
    for (int u = 0; u < 30; ++u) {
        int i = t + NTHR * u;            // 0..7679, Ww is [384][20] row-major
        sB[i] = Ww[i];
    }
    float invgn = 1.0f / sqrtf(ws[0]);   // global Frobenius norm of r
    if (t < TM) {
        int eg = sPerm[t];
        float rx = r[eg * 3 + 0], ry = r[eg * 3 + 1], rz = r[eg * 3 + 2];
        float rn = sqrtf(rx * rx + ry * ry + rz * rz);
        sOrg[t * 3 + 0] = rx * invgn;
        sOrg[t * 3 + 1] = ry * invgn;
        sOrg[t * 3 + 2] = rz * invgn;
        sIdx[t] = idx_i[eg];
        const float c1 = 3.14159265358979323846f / 5.0f;
        float invrn = 1.0f / rn;
        #pragma unroll
        for (int n = 0; n < NRB; ++n) {
            float rbf = sinf((float)(n + 1) * c1 * rn) * invrn;
            sFc[t * NRB + n] = (rbf <= 5.0f) ? 0.5f * (cosf(rbf * c1) + 1.0f) : 0.0f;
        }
    }
    __syncthreads();

    // ================= phase 3: w = fcut @ Ww^T + bw ; split; aggregated scatter ==
    float bwv[12];
    #pragma unroll
    for (int j = 0; j < 4; ++j)
        #pragma unroll
        for (int c = 0; c < 3; ++c)
            bwv[j * 3 + c] = bw[td + 32 * j + 128 * c];

    float* out_v = out;                                   // N*3*128
    float* out_s = out + (size_t)NNODE * 3 * DD;          // N*128

    // edges within this thread's group are node-sorted; aggregate runs in
    // registers and flush one atomicAdd set per distinct node.
    int curNode = sIdx[e2];
    float aS[4];
    float aV[4][3];
    #pragma unroll
    for (int j = 0; j < 4; ++j) {
        aS[j] = 0.f;
        aV[j][0] = 0.f; aV[j][1] = 0.f; aV[j][2] = 0.f;
    }

    #pragma unroll 1
    for (int i = 0; i < 8; ++i) {
        int el   = e2 + i;
        int node = sIdx[el];
        if (node != curNode) {           // flush accumulated run (uniform per half-wave)
            #pragma unroll
            for (int j = 0; j < 4; ++j) {
                int d = td + 32 * j;
                atomicAdd(&out_s[(size_t)curNode * DD + d], aS[j]);
                atomicAdd(&out_v[((size_t)curNode * 3 + 0) * DD + d], aV[j][0]);
                atomicAdd(&out_v[((size_t)curNode * 3 + 1) * DD + d], aV[j][1]);
                atomicAdd(&out_v[((size_t)curNode * 3 + 2) * DD + d], aV[j][2]);
                aS[j] = 0.f;
                aV[j][0] = 0.f; aV[j][1] = 0.f; aV[j][2] = 0.f;
            }
            curNode = node;
        }
        int eg = sPerm[el];
        float fc[NRB];
        #pragma unroll
        for (int n4 = 0; n4 < 5; ++n4) {
            float4 f4 = *reinterpret_cast<const float4*>(&sFc[el * NRB + n4 * 4]);
            fc[n4 * 4 + 0] = f4.x; fc[n4 * 4 + 1] = f4.y;
            fc[n4 * 4 + 2] = f4.z; fc[n4 * 4 + 3] = f4.w;
        }
        float o0 = sOrg[el * 3 + 0], o1 = sOrg[el * 3 + 1], o2 = sOrg[el * 3 + 2];
        const float* vrow = &v[(size_t)eg * 3 * DD];
        #pragma unroll
        for (int j = 0; j < 4; ++j) {
            float spj[3];
            #pragma unroll
            for (int c = 0; c < 3; ++c) {
                int g = td + 32 * j + 128 * c;
                const float4* wr4 = reinterpret_cast<const float4*>(&sB[g * 20]);
                float w = bwv[j * 3 + c];
                #pragma unroll
                for (int n4 = 0; n4 < 5; ++n4) {
                    float4 wv = wr4[n4];
                    w += fc[n4 * 4 + 0] * wv.x + fc[n4 * 4 + 1] * wv.y
                       + fc[n4 * 4 + 2] * wv.z + fc[n4 * 4 + 3] * wv.w;
                }
                spj[c] = w * acc2[i][j * 3 + c];
            }
            int d = td + 32 * j;
            aS[j]    += spj[1];
            aV[j][0] += spj[2] * o0 + spj[0] * vrow[0 * DD + d];
            aV[j][1] += spj[2] * o1 + spj[0] * vrow[1 * DD + d];
            aV[j][2] += spj[2] * o2 + spj[0] * vrow[2 * DD + d];
        }
    }
    // final flush
    #pragma unroll
    for (int j = 0; j < 4; ++j) {
        int d = td + 32 * j;
        atomicAdd(&out_s[(size_t)curNode * DD + d], aS[j]);
        atomicAdd(&out_v[((size_t)curNode * 3 + 0) * DD + d], aV[j][0]);
        atomicAdd(&out_v[((size_t)curNode * 3 + 1) * DD + d], aV[j][1]);
        atomicAdd(&out_v[((size_t)curNode * 3 + 2) * DD + d], aV[j][2]);
    }
}

extern "C" void kernel_launch(void* const* d_in, const int* in_sizes, int n_in,
                              void* d_out, int out_size, void* d_ws, size_t ws_size,
                              hipStream_t stream) {
    const float* s  = (const float*)d_in[0];
    const float* r  = (const float*)d_in[1];
    const float* v  = (const float*)d_in[2];
    const float* W1 = (const float*)d_in[3];
    const float* b1 = (const float*)d_in[4];
    const float* W2 = (const float*)d_in[5];
    const float* b2 = (const float*)d_in[6];
    const float* Ww = (const float*)d_in[7];
    const float* bw = (const float*)d_in[8];
    const int* idx  = (const int*)d_in[9];
    float* out = (float*)d_out;
    float* ws  = (float*)d_ws;

    hipMemsetAsync(d_out, 0, (size_t)out_size * sizeof(float), stream);
    hipMemsetAsync(d_ws, 0, sizeof(float), stream);
    zero_kernel<<<(NNODE + NTHR - 1) / NTHR, NTHR, 0, stream>>>();
    prep_kernel<<<256, NTHR, 0, stream>>>(r, idx, ws);
    scan_kernel<<<1, NTHR, 0, stream>>>();
    scatter_kernel<<<128, NTHR, 0, stream>>>(idx);
    fused_kernel<<<E_TOT / TM, NTHR, 0, stream>>>(s, r, v, W1, b1, W2, b2, Ww, bw, idx, ws, out);
}

// Round 3
// 2043.608 us; speedup vs baseline: 1.3141x; 1.3141x over previous
//
#include <hip/hip_runtime.h>
#include <math.h>

#define E_TOT 200000
#define NNODE 12500
#define DD 128
#define G3 384
#define NRB 20
#define TM 64            // edges per block tile
#define NTHR 256

// ---- device scratch for counting sort (avoids workspace-size assumptions) ----
__device__ int d_cnt[NNODE];
__device__ int d_offs[NNODE];
__device__ int d_perm[E_TOT];

// ---------------- kernel 0: zero the histogram --------------------------------
__global__ void zero_kernel() {
    int i = blockIdx.x * blockDim.x + threadIdx.x;
    if (i < NNODE) d_cnt[i] = 0;
}

// ---------------- kernel 1: global sum-of-squares of r + node histogram -------
__global__ void prep_kernel(const float* __restrict__ r,
                            const int* __restrict__ idx_i,
                            float* __restrict__ ws) {
    const int tid = blockIdx.x * blockDim.x + threadIdx.x;
    const int stride = gridDim.x * blockDim.x;
    const int n = E_TOT * 3;
    float acc = 0.f;
    for (int i = tid; i < n; i += stride) {
        float x = r[i];
        acc += x * x;
    }
    #pragma unroll
    for (int off = 32; off > 0; off >>= 1)
        acc += __shfl_down(acc, off, 64);
    __shared__ float wsum[4];
    int lane = threadIdx.x & 63, wid = threadIdx.x >> 6;
    if (lane == 0) wsum[wid] = acc;
    __syncthreads();
    if (threadIdx.x == 0)
        atomicAdd(ws, wsum[0] + wsum[1] + wsum[2] + wsum[3]);
    for (int e = tid; e < E_TOT; e += stride)
        atomicAdd(&d_cnt[idx_i[e]], 1);
}

// ---------------- kernel 2: exclusive prefix sum over 12500 bins --------------
__global__ void scan_kernel() {
    __shared__ int part[NTHR];
    const int per = (NNODE + NTHR - 1) / NTHR;   // 49
    const int t = threadIdx.x;
    const int lo = t * per;
    const int hi = (lo + per < NNODE) ? lo + per : NNODE;
    int sum = 0;
    for (int i = lo; i < hi; ++i) sum += d_cnt[i];
    part[t] = sum;
    __syncthreads();
    if (t == 0) {
        int acc = 0;
        for (int k = 0; k < NTHR; ++k) { int c = part[k]; part[k] = acc; acc += c; }
    }
    __syncthreads();
    int acc = part[t];
    for (int i = lo; i < hi; ++i) { int c = d_cnt[i]; d_offs[i] = acc; acc += c; }
}

// ---------------- kernel 3: scatter edge ids into node-sorted order -----------
__global__ void scatter_kernel(const int* __restrict__ idx_i) {
    const int tid = blockIdx.x * blockDim.x + threadIdx.x;
    const int stride = gridDim.x * blockDim.x;
    for (int e = tid; e < E_TOT; e += stride) {
        int p = atomicAdd(&d_offs[idx_i[e]], 1);
        d_perm[p] = e;
    }
}

// ---------------- kernel 4: fused MLP + gating + aggregated scatter -----------
// Spill-free restructure: phase 2+3 split into 3 passes over the 128-column
// output groups (out_v/out_s terms are additive-separable). Per-pass
// accumulator acc[8][4] = 32 VGPRs (was acc2[8][12] = 96 -> spilled at the
// 128-VGPR cap, producing ~7 GB of scratch write-back per dispatch).
// LDS 50.4 KB -> 3 blocks/CU.
__global__ __launch_bounds__(NTHR, 3) void fused_kernel(
    const float* __restrict__ s, const float* __restrict__ r,
    const float* __restrict__ v, const float* __restrict__ W1,
    const float* __restrict__ b1, const float* __restrict__ W2,
    const float* __restrict__ b2, const float* __restrict__ Ww,
    const float* __restrict__ bw, const int* __restrict__ idx_i,
    const float* __restrict__ ws, float* __restrict__ out)
{
    __shared__ float sS[TM][DD + 4];     // 64 x 132 = 33792 B : S tile, then H
    __shared__ float sB[128 * 20];       // 10240 B : W1/W2 chunk or Ww slice
    __shared__ float sFc[TM * NRB];      // 5120 B
    __shared__ float sOrg[TM * 3];       // 768 B
    __shared__ int   sIdx[TM];           // 256 B
    __shared__ int   sPerm[TM];          // 256 B

    const int t   = threadIdx.x;
    const int e0g = blockIdx.x * TM;

    if (t < TM) sPerm[t] = d_perm[e0g + t];
    __syncthreads();

    // ---- stage S tile (64 x 128 f32), coalesced float4 per row ----
    #pragma unroll
    for (int u = 0; u < 8; ++u) {
        int fi   = t + NTHR * u;         // float4 index 0..2047
        int row  = fi >> 5;              // 32 float4 per row
        int col4 = fi & 31;
        float4 val = reinterpret_cast<const float4*>(s)[(size_t)sPerm[row] * 32 + col4];
        *reinterpret_cast<float4*>(&sS[row][col4 * 4]) = val;
    }

    // ---- fcut / org / idx (dedicated LDS; survives all passes) ----
    float invgn = 1.0f / sqrtf(ws[0]);   // global Frobenius norm of r
    if (t < TM) {
        int eg = sPerm[t];
        float rx = r[eg * 3 + 0], ry = r[eg * 3 + 1], rz = r[eg * 3 + 2];
        float rn = sqrtf(rx * rx + ry * ry + rz * rz);
        sOrg[t * 3 + 0] = rx * invgn;
        sOrg[t * 3 + 1] = ry * invgn;
        sOrg[t * 3 + 2] = rz * invgn;
        sIdx[t] = idx_i[eg];
        const float c1 = 3.14159265358979323846f / 5.0f;
        float invrn = 1.0f / rn;
        #pragma unroll
        for (int n = 0; n < NRB; ++n) {
            float rbf = sinf((float)(n + 1) * c1 * rn) * invrn;
            sFc[t * NRB + n] = (rbf <= 5.0f) ? 0.5f * (cosf(rbf * c1) + 1.0f) : 0.0f;
        }
    }

    // ================= phase 1: H = silu(S @ W1^T + b1) =================
    const int tf  = t & 15;              // f lane base; f = tf + 16*j
    const int te1 = t >> 4;              // 0..15
    const int e1  = te1 * 4;             // 4 edges per thread
    float acc1[4][8];
    #pragma unroll
    for (int j = 0; j < 8; ++j) {
        float bias = b1[tf + 16 * j];
        #pragma unroll
        for (int i = 0; i < 4; ++i) acc1[i][j] = bias;
    }
    for (int kk = 0; kk < DD; kk += 16) {
        __syncthreads();                 // prev chunk reads done (also covers staging)
        {   // load W1 chunk rows f=0..127, k'=0..15 into sB[f*20 + k']
            int f = t >> 1;
            int kb = (t & 1) * 8;
            const float4* src = reinterpret_cast<const float4*>(&W1[f * DD + kk + kb]);
            float4 v0 = src[0], v1 = src[1];
            *reinterpret_cast<float4*>(&sB[f * 20 + kb])     = v0;
            *reinterpret_cast<float4*>(&sB[f * 20 + kb + 4]) = v1;
        }
        __syncthreads();
        #pragma unroll
        for (int u = 0; u < 4; ++u) {
            float4 a[4], b[8];
            #pragma unroll
            for (int i = 0; i < 4; ++i)
                a[i] = *reinterpret_cast<const float4*>(&sS[e1 + i][kk + 4 * u]);
            #pragma unroll
            for (int j = 0; j < 8; ++j)
                b[j] = *reinterpret_cast<const float4*>(&sB[(tf + 16 * j) * 20 + 4 * u]);
            #pragma unroll
            for (int i = 0; i < 4; ++i)
                #pragma unroll
                for (int j = 0; j < 8; ++j)
                    acc1[i][j] += a[i].x * b[j].x + a[i].y * b[j].y
                                + a[i].z * b[j].z + a[i].w * b[j].w;
        }
    }
    __syncthreads();
    // silu, write H back into sS (S dead)
    #pragma unroll
    for (int i = 0; i < 4; ++i)
        #pragma unroll
        for (int j = 0; j < 8; ++j) {
            float x = acc1[i][j];
            sS[e1 + i][tf + 16 * j] = x / (1.0f + expf(-x));
        }

    // ============ phases 2+3: three passes over output groups c=0,1,2 ============
    const int td  = t & 31;              // d lane; d = td + 32*j
    const int te2 = t >> 5;              // 0..7
    const int e2  = te2 * 8;             // 8 edges per thread

    float* out_v = out;                                   // N*3*128
    float* out_s = out + (size_t)NNODE * 3 * DD;          // N*128

    for (int c = 0; c < 3; ++c) {
        // ---- GEMM: acc[i][j] = (H @ W2_c^T + b2_c)[e2+i][td+32j] ----
        float acc[8][4];
        #pragma unroll
        for (int j = 0; j < 4; ++j) {
            float bias = b2[c * DD + td + 32 * j];
            #pragma unroll
            for (int i = 0; i < 8; ++i) acc[i][j] = bias;
        }
        for (int kk = 0; kk < DD; kk += 16) {
            __syncthreads();             // prior sB reads done
            {   // stage W2 rows c*128..c*128+127, k'=kk..kk+15
                #pragma unroll
                for (int u = 0; u < 2; ++u) {
                    int fi = t + NTHR * u;   // 0..511 float4s
                    int g  = fi >> 2;        // 0..127
                    int k4 = (fi & 3) * 4;
                    float4 val = *reinterpret_cast<const float4*>(
                        &W2[(size_t)(c * DD + g) * DD + kk + k4]);
                    *reinterpret_cast<float4*>(&sB[g * 20 + k4]) = val;
                }
            }
            __syncthreads();
            #pragma unroll
            for (int u = 0; u < 4; ++u) {
                float4 bfr[4];
                #pragma unroll
                for (int j = 0; j < 4; ++j)
                    bfr[j] = *reinterpret_cast<const float4*>(
                        &sB[(td + 32 * j) * 20 + 4 * u]);
                #pragma unroll
                for (int i = 0; i < 8; ++i) {
                    float4 a = *reinterpret_cast<const float4*>(&sS[e2 + i][kk + 4 * u]);
                    #pragma unroll
                    for (int j = 0; j < 4; ++j)
                        acc[i][j] += a.x * bfr[j].x + a.y * bfr[j].y
                                   + a.z * bfr[j].z + a.w * bfr[j].w;
                }
            }
        }
        __syncthreads();                 // kk-loop sB reads done
        // ---- stage Ww slice rows c*128..c*128+127 (contiguous 2560 floats) ----
        #pragma unroll
        for (int u = 0; u < 10; ++u) {
            int i = t + NTHR * u;        // 0..2559
            sB[i] = Ww[c * (DD * NRB) + i];
        }
        __syncthreads();

        // ---- gating + run-merged scatter for this pass ----
        float bwv[4];
        #pragma unroll
        for (int j = 0; j < 4; ++j) bwv[j] = bw[c * DD + td + 32 * j];

        int curNode = sIdx[e2];
        if (c == 1) {
            float aS[4] = {0.f, 0.f, 0.f, 0.f};
            #pragma unroll 1
            for (int i = 0; i < 8; ++i) {
                int el   = e2 + i;
                int node = sIdx[el];
                if (node != curNode) {
                    #pragma unroll
                    for (int j = 0; j < 4; ++j) {
                        atomicAdd(&out_s[(size_t)curNode * DD + td + 32 * j], aS[j]);
                        aS[j] = 0.f;
                    }
                    curNode = node;
                }
                float fc[NRB];
                #pragma unroll
                for (int n4 = 0; n4 < 5; ++n4) {
                    float4 f4 = *reinterpret_cast<const float4*>(&sFc[el * NRB + n4 * 4]);
                    fc[n4 * 4 + 0] = f4.x; fc[n4 * 4 + 1] = f4.y;
                    fc[n4 * 4 + 2] = f4.z; fc[n4 * 4 + 3] = f4.w;
                }
                #pragma unroll
                for (int j = 0; j < 4; ++j) {
                    const float4* wr4 = reinterpret_cast<const float4*>(
                        &sB[(td + 32 * j) * NRB]);
                    float w = bwv[j];
                    #pragma unroll
                    for (int n4 = 0; n4 < 5; ++n4) {
                        float4 wv = wr4[n4];
                        w += fc[n4 * 4 + 0] * wv.x + fc[n4 * 4 + 1] * wv.y
                           + fc[n4 * 4 + 2] * wv.z + fc[n4 * 4 + 3] * wv.w;
                    }
                    aS[j] += w * acc[i][j];
                }
            }
            #pragma unroll
            for (int j = 0; j < 4; ++j)
                atomicAdd(&out_s[(size_t)curNode * DD + td + 32 * j], aS[j]);
        } else {
            // c==0: out_v += s0 * v[edge] ; c==2: out_v += s2 * org[edge]
            float aV[4][3];
            #pragma unroll
            for (int j = 0; j < 4; ++j) {
                aV[j][0] = 0.f; aV[j][1] = 0.f; aV[j][2] = 0.f;
            }
            #pragma unroll 1
            for (int i = 0; i < 8; ++i) {
                int el   = e2 + i;
                int node = sIdx[el];
                if (node != curNode) {
                    #pragma unroll
                    for (int j = 0; j < 4; ++j) {
                        int d = td + 32 * j;
                        atomicAdd(&out_v[((size_t)curNode * 3 + 0) * DD + d], aV[j][0]);
                        atomicAdd(&out_v[((size_t)curNode * 3 + 1) * DD + d], aV[j][1]);
                        atomicAdd(&out_v[((size_t)curNode * 3 + 2) * DD + d], aV[j][2]);
                        aV[j][0] = 0.f; aV[j][1] = 0.f; aV[j][2] = 0.f;
                    }
                    curNode = node;
                }
                float fc[NRB];
                #pragma unroll
                for (int n4 = 0; n4 < 5; ++n4) {
                    float4 f4 = *reinterpret_cast<const float4*>(&sFc[el * NRB + n4 * 4]);
                    fc[n4 * 4 + 0] = f4.x; fc[n4 * 4 + 1] = f4.y;
                    fc[n4 * 4 + 2] = f4.z; fc[n4 * 4 + 3] = f4.w;
                }
                if (c == 0) {
                    int eg = sPerm[el];
                    const float* vrow = &v[(size_t)eg * 3 * DD];
                    #pragma unroll
                    for (int j = 0; j < 4; ++j) {
                        const float4* wr4 = reinterpret_cast<const float4*>(
                            &sB[(td + 32 * j) * NRB]);
                        float w = bwv[j];
                        #pragma unroll
                        for (int n4 = 0; n4 < 5; ++n4) {
                            float4 wv = wr4[n4];
                            w += fc[n4 * 4 + 0] * wv.x + fc[n4 * 4 + 1] * wv.y
                               + fc[n4 * 4 + 2] * wv.z + fc[n4 * 4 + 3] * wv.w;
                        }
                        float s0 = w * acc[i][j];
                        int d = td + 32 * j;
                        aV[j][0] += s0 * vrow[0 * DD + d];
                        aV[j][1] += s0 * vrow[1 * DD + d];
                        aV[j][2] += s0 * vrow[2 * DD + d];
                    }
                } else {
                    float o0 = sOrg[el * 3 + 0], o1 = sOrg[el * 3 + 1],
                          o2 = sOrg[el * 3 + 2];
                    #pragma unroll
                    for (int j = 0; j < 4; ++j) {
                        const float4* wr4 = reinterpret_cast<const float4*>(
                            &sB[(td + 32 * j) * NRB]);
                        float w = bwv[j];
                        #pragma unroll
                        for (int n4 = 0; n4 < 5; ++n4) {
                            float4 wv = wr4[n4];
                            w += fc[n4 * 4 + 0] * wv.x + fc[n4 * 4 + 1] * wv.y
                               + fc[n4 * 4 + 2] * wv.z + fc[n4 * 4 + 3] * wv.w;
                        }
                        float s2 = w * acc[i][j];
                        aV[j][0] += s2 * o0;
                        aV[j][1] += s2 * o1;
                        aV[j][2] += s2 * o2;
                    }
                }
            }
            #pragma unroll
            for (int j = 0; j < 4; ++j) {
                int d = td + 32 * j;
                atomicAdd(&out_v[((size_t)curNode * 3 + 0) * DD + d], aV[j][0]);
                atomicAdd(&out_v[((size_t)curNode * 3 + 1) * DD + d], aV[j][1]);
                atomicAdd(&out_v[((size_t)curNode * 3 + 2) * DD + d], aV[j][2]);
            }
        }
    }
}

extern "C" void kernel_launch(void* const* d_in, const int* in_sizes, int n_in,
                              void* d_out, int out_size, void* d_ws, size_t ws_size,
                              hipStream_t stream) {
    const float* s  = (const float*)d_in[0];
    const float* r  = (const float*)d_in[1];
    const float* v  = (const float*)d_in[2];
    const float* W1 = (const float*)d_in[3];
    const float* b1 = (const float*)d_in[4];
    const float* W2 = (const float*)d_in[5];
    const float* b2 = (const float*)d_in[6];
    const float* Ww = (const float*)d_in[7];
    const float* bw = (const float*)d_in[8];
    const int* idx  = (const int*)d_in[9];
    float* out = (float*)d_out;
    float* ws  = (float*)d_ws;

    hipMemsetAsync(d_out, 0, (size_t)out_size * sizeof(float), stream);
    hipMemsetAsync(d_ws, 0, sizeof(float), stream);
    zero_kernel<<<(NNODE + NTHR - 1) / NTHR, NTHR, 0, stream>>>();
    prep_kernel<<<256, NTHR, 0, stream>>>(r, idx, ws);
    scan_kernel<<<1, NTHR, 0, stream>>>();
    scatter_kernel<<<128, NTHR, 0, stream>>>(idx);
    fused_kernel<<<E_TOT / TM, NTHR, 0, stream>>>(s, r, v, W1, b1, W2, b2, Ww, bw, idx, ws, out);
}